// Round 4
// baseline (37.493 us; speedup 1.0000x reference)
//
#include <hip/hip_runtime.h>
#include <hip/hip_bf16.h>
#include <stdint.h>

// RelativePositionalEmbedding: out[bh, q, k] = dot(q[bh,q,:], pos_emb[q-k+1023,:]) / 8
// B*H = 32, L = 1024, D = 64. Output (32,1024,1024) fp32 = 134 MB -> write-BW-bound.
//
// R3: (1) cvt shrunk to P-only; Q read as fp32 + converted in-register in rpe
//     (saves ~3us of cvt traffic/launch). (2) Non-temporal stores (nt flag):
//     output is write-once, every 128B line fully covered per store inst ->
//     stream past L2 write-allocate. (3) vmcnt FIFO re-derived with STAGE
//     issued before flush so counted waits never drain flush stores.

#define LSEQ 1024
#define DDIM 64

typedef __attribute__((ext_vector_type(8))) short bf16x8;
typedef __attribute__((ext_vector_type(16))) float f32x16;

__device__ __forceinline__ unsigned short f2b(float f) {
  union { float f; unsigned u; } c; c.f = f;
  unsigned u = c.u;
  u += 0x7fffu + ((u >> 16) & 1u);   // round-to-nearest-even
  return (unsigned short)(u >> 16);
}

// Convert pos_emb to bf16 in workspace: 131,008 f32 = 32,752 float4.
__global__ __launch_bounds__(256) void cvt_p_kernel(
    const float4* __restrict__ p4, ushort4* __restrict__ pb) {
  int j = blockIdx.x * 256 + threadIdx.x;
  if (j < 32752) {
    float4 v = p4[j];
    ushort4 o;
    o.x = f2b(v.x); o.y = f2b(v.y); o.z = f2b(v.z); o.w = f2b(v.w);
    pb[j] = o;
  }
}

// One workgroup (4 waves) per q. Wave w owns columns [w*256, w*256+256), 8 tiles.
// mfma_f32_32x32x16_bf16: A row = lane&31, k = 16*s + 8*(lane>>5)+j
//                         B col = lane&31 (-> P row q+1023-n), same k
//                         D col = lane&31, row = (r&3)+8*(r>>2)+4*(lane>>5)
__global__ __launch_bounds__(256) void rpe_kernel(
    const float* __restrict__ Qf, const short* __restrict__ Pb,
    float* __restrict__ out) {
  __shared__ short lds[4][2][2048];           // [wave][buf][4KB band]
  // XCD-chunked q: XCD x gets q in [x*128, x*128+128) (1024 = 8*128, bijective)
  const int bid  = (int)blockIdx.x;
  const int q    = ((bid & 7) << 7) + (bid >> 3);
  const int tid  = (int)threadIdx.x;
  const int lane = tid & 63;
  const int wave = tid >> 6;
  const int l31  = lane & 31;
  const int hi   = lane >> 5;
  const int nbase = wave << 8;

  // pre-swizzled gload_lds SOURCE offset (rule #21): row-in-8 = lane>>3,
  // col16 = (lane&7) ^ (lane>>3); LDS dest stays linear lane*16.
  const int lane_off = ((lane >> 3) << 7) + ((((lane & 7) ^ (lane >> 3))) << 4);
  const char* Pc = (const char*)Pb;           // P row stride 128B

  auto STAGE = [&](int tt, int buf) {
    const int lo = q + 992 - nbase - (tt << 5);   // band rows [lo, lo+31]
    const char* src = Pc + ((size_t)lo << 7) + lane_off;
#pragma unroll
    for (int j = 0; j < 4; ++j)
      __builtin_amdgcn_global_load_lds(
          (const __attribute__((address_space(1))) void*)(src + (j << 10)),
          (__attribute__((address_space(3))) void*)&lds[wave][buf][j << 9],
          16, 0, 0);
  };

  STAGE(0, 0);                                // vm: stage0 (4)

  // A fragments from fp32 Q, scaled by 1/8 (exact) and converted in-register.
  // Qf[m = l31][q][16s + 8hi + j], j = 0..7 -> 2 x dwordx4 per s.
  bf16x8 a[4];
  {
    const float* qp = Qf + ((size_t)((l31 << 10) + q)) * DDIM + (hi << 3);
#pragma unroll
    for (int s = 0; s < 4; ++s) {
      float4 u = *(const float4*)(qp + 16 * s);
      float4 v = *(const float4*)(qp + 16 * s + 4);
      bf16x8 t;
      t[0] = (short)f2b(u.x * 0.125f); t[1] = (short)f2b(u.y * 0.125f);
      t[2] = (short)f2b(u.z * 0.125f); t[3] = (short)f2b(u.w * 0.125f);
      t[4] = (short)f2b(v.x * 0.125f); t[5] = (short)f2b(v.y * 0.125f);
      t[6] = (short)f2b(v.z * 0.125f); t[7] = (short)f2b(v.w * 0.125f);
      a[s] = t;
    }
  }                                           // vm: Q (8)

  STAGE(1, 1);                                // vm: stage1 (4)

  const int rr = 31 - l31;                    // LDS row this lane reads
  const int rx = rr & 7;                      // its XOR key

  f32x16 accA, accB;
#pragma unroll
  for (int t = 0; t < 8; ++t) {
    // FIFO-derived counted waits (stage(t) must complete; stores NEVER drained
    // mid-loop since STAGE is issued before each flush):
    // t=0: [stage0(4),Q(8),stage1(4)] -> drain stage0+Q -> vmcnt(4)
    // t=1: [stage1(4),stage2(4)]      -> vmcnt(4)
    // t=2..6: remaining <= 32 stores + 4 stage -> vmcnt(36)
    // t=7: remaining <= 32 stores -> vmcnt(32)
    if (t == 0 || t == 1)
      asm volatile("s_waitcnt vmcnt(4)" ::: "memory");
    else if (t == 7)
      asm volatile("s_waitcnt vmcnt(32)" ::: "memory");
    else
      asm volatile("s_waitcnt vmcnt(36)" ::: "memory");

    f32x16& acc = (t & 1) ? accB : accA;
#pragma unroll
    for (int r = 0; r < 16; ++r) acc[r] = 0.0f;

    const short* base = &lds[wave][t & 1][rr << 6];
#pragma unroll
    for (int s = 0; s < 4; ++s) {
      bf16x8 bfr = *(const bf16x8*)(base + (((hi + 2 * s) ^ rx) << 3));
      acc = __builtin_amdgcn_mfma_f32_32x32x16_bf16(a[s], bfr, acc, 0, 0, 0);
    }

    if (t < 6) STAGE(t + 2, t & 1);           // refill consumed buffer FIRST

    if (t & 1) {
      // flush tiles (t-1, t): per m-plane two adjacent 128B lines = 256B run,
      // non-temporal (write-once output, lines fully covered per store inst)
      float* ob = out + ((size_t)hi << 22) + (q << 10) + nbase + ((t - 1) << 5) + l31;
#pragma unroll
      for (int r = 0; r < 16; ++r) {
        const int m = (r & 3) + 8 * (r >> 2);
        __builtin_nontemporal_store(accA[r], ob + ((size_t)m << 20));
        __builtin_nontemporal_store(accB[r], ob + ((size_t)m << 20) + 32);
      }
    }
  }
}

extern "C" void kernel_launch(void* const* d_in, const int* in_sizes, int n_in,
                              void* d_out, int out_size, void* d_ws, size_t ws_size,
                              hipStream_t stream) {
  const float* qin = (const float*)d_in[0];
  // d_in[1] (k) unused: only its length (1024) matters, which is fixed.
  const float* pin = (const float*)d_in[2];

  short* pb = (short*)d_ws;                  // 131,008 bf16 = 262 KB

  cvt_p_kernel<<<128, 256, 0, stream>>>((const float4*)pin, (ushort4*)pb);
  rpe_kernel<<<1024, 256, 0, stream>>>(qin, pb, (float*)d_out);
}

// Round 6
// 36.334 us; speedup vs baseline: 1.0319x; 1.0319x over previous
//
#include <hip/hip_runtime.h>
#include <hip/hip_bf16.h>
#include <stdint.h>

// RelativePositionalEmbedding: out[bh, q, k] = dot(q[bh,q,:], pos_emb[q-k+1023,:]) / 8
// B*H = 32, L = 1024, D = 64. Output (32,1024,1024) fp32 = 134 MB -> write-BW-bound.
//
// R5 = R4 + the one-line FIFO fix: at t=7 only stage7's 4 loads are
// outstanding, so vmcnt(4) was a no-op -> race (absmax 7.4). t=7 now vmcnt(0).
// Structure: acc[8] in registers (static-indexed), single end-flush with
// tt-inner ordering -> 1KiB contiguous per m-plane; no stores in the K-loop.

#define LSEQ 1024
#define DDIM 64

typedef __attribute__((ext_vector_type(8))) short bf16x8;
typedef __attribute__((ext_vector_type(16))) float f32x16;

__device__ __forceinline__ unsigned short f2b(float f) {
  union { float f; unsigned u; } c; c.f = f;
  unsigned u = c.u;
  u += 0x7fffu + ((u >> 16) & 1u);   // round-to-nearest-even
  return (unsigned short)(u >> 16);
}

// Convert pos_emb to bf16 in workspace: 131,008 f32 = 32,752 float4.
__global__ __launch_bounds__(256) void cvt_p_kernel(
    const float4* __restrict__ p4, ushort4* __restrict__ pb) {
  int j = blockIdx.x * 256 + threadIdx.x;
  if (j < 32752) {
    float4 v = p4[j];
    ushort4 o;
    o.x = f2b(v.x); o.y = f2b(v.y); o.z = f2b(v.z); o.w = f2b(v.w);
    pb[j] = o;
  }
}

// One workgroup (4 waves) per q. Wave w owns columns [w*256, w*256+256), 8 tiles.
// mfma_f32_32x32x16_bf16: A row = lane&31, k = 16*s + 8*(lane>>5)+j
//                         B col = lane&31 (-> P row q+1023-n), same k
//                         D col = lane&31, row = (r&3)+8*(r>>2)+4*(lane>>5)
__global__ __launch_bounds__(256) void rpe_kernel(
    const float* __restrict__ Qf, const short* __restrict__ Pb,
    float* __restrict__ out) {
  __shared__ short lds[4][2][2048];           // [wave][buf][4KB band]
  // XCD-chunked q: XCD x gets q in [x*128, x*128+128) (1024 = 8*128, bijective)
  const int bid  = (int)blockIdx.x;
  const int q    = ((bid & 7) << 7) + (bid >> 3);
  const int tid  = (int)threadIdx.x;
  const int lane = tid & 63;
  const int wave = tid >> 6;
  const int l31  = lane & 31;
  const int hi   = lane >> 5;
  const int nbase = wave << 8;

  // pre-swizzled gload_lds SOURCE offset (rule #21): row-in-8 = lane>>3,
  // col16 = (lane&7) ^ (lane>>3); LDS dest stays linear lane*16.
  const int lane_off = ((lane >> 3) << 7) + ((((lane & 7) ^ (lane >> 3))) << 4);
  const char* Pc = (const char*)Pb;           // P row stride 128B

  auto STAGE = [&](int tt, int buf) {
    const int lo = q + 992 - nbase - (tt << 5);   // band rows [lo, lo+31]
    const char* src = Pc + ((size_t)lo << 7) + lane_off;
#pragma unroll
    for (int j = 0; j < 4; ++j)
      __builtin_amdgcn_global_load_lds(
          (const __attribute__((address_space(1))) void*)(src + (j << 10)),
          (__attribute__((address_space(3))) void*)&lds[wave][buf][j << 9],
          16, 0, 0);
  };

  STAGE(0, 0);                                // vm: stage0 (4)

  // A fragments from fp32 Q, scaled by 1/8 (exact) and converted in-register.
  // Qf[m = l31][q][16s + 8hi + j], j = 0..7 -> 2 x dwordx4 per s.
  bf16x8 a[4];
  {
    const float* qp = Qf + ((size_t)((l31 << 10) + q)) * DDIM + (hi << 3);
#pragma unroll
    for (int s = 0; s < 4; ++s) {
      float4 u = *(const float4*)(qp + 16 * s);
      float4 v = *(const float4*)(qp + 16 * s + 4);
      bf16x8 t;
      t[0] = (short)f2b(u.x * 0.125f); t[1] = (short)f2b(u.y * 0.125f);
      t[2] = (short)f2b(u.z * 0.125f); t[3] = (short)f2b(u.w * 0.125f);
      t[4] = (short)f2b(v.x * 0.125f); t[5] = (short)f2b(v.y * 0.125f);
      t[6] = (short)f2b(v.z * 0.125f); t[7] = (short)f2b(v.w * 0.125f);
      a[s] = t;
    }
  }                                           // vm: Q (8)

  STAGE(1, 1);                                // vm: stage1 (4)

  const int rr = 31 - l31;                    // LDS row this lane reads
  const int rx = rr & 7;                      // its XOR key

  f32x16 acc[8];                              // 128 VGPR, static-indexed only
#pragma unroll
  for (int t = 0; t < 8; ++t) {
    // FIFO at top of iter t (no stores in loop):
    //   t=0: stage0(4)+Q(8)+stage1(4): vmcnt(4) drains stage0+Q.
    //   t=1..6: stage(t)(4)+stage(t+1)(4): vmcnt(4) drains stage(t).
    //   t=7: ONLY stage7(4) outstanding -> must drain fully: vmcnt(0).
    if (t == 7)
      asm volatile("s_waitcnt vmcnt(0)" ::: "memory");
    else
      asm volatile("s_waitcnt vmcnt(4)" ::: "memory");

#pragma unroll
    for (int r = 0; r < 16; ++r) acc[t][r] = 0.0f;

    const short* base = &lds[wave][t & 1][rr << 6];
#pragma unroll
    for (int s = 0; s < 4; ++s) {
      bf16x8 bfr = *(const bf16x8*)(base + (((hi + 2 * s) ^ rx) << 3));
      acc[t] = __builtin_amdgcn_mfma_f32_32x32x16_bf16(a[s], bfr, acc[t], 0, 0, 0);
    }

    if (t < 6) STAGE(t + 2, t & 1);           // refill consumed buffer
  }

  // Final flush: tt-inner => per m-plane 8 back-to-back 128B store insts
  // covering n = [nbase, nbase+256) -> 1KiB contiguous run per plane.
  float* ob0 = out + ((size_t)hi << 22) + (q << 10) + nbase + l31;
#pragma unroll
  for (int r = 0; r < 16; ++r) {
    const int m = (r & 3) + 8 * (r >> 2);
    float* obp = ob0 + ((size_t)m << 20);
#pragma unroll
    for (int tt = 0; tt < 8; ++tt)
      obp[tt << 5] = acc[tt][r];
  }
}

extern "C" void kernel_launch(void* const* d_in, const int* in_sizes, int n_in,
                              void* d_out, int out_size, void* d_ws, size_t ws_size,
                              hipStream_t stream) {
  const float* qin = (const float*)d_in[0];
  // d_in[1] (k) unused: only its length (1024) matters, which is fixed.
  const float* pin = (const float*)d_in[2];

  short* pb = (short*)d_ws;                  // 131,008 bf16 = 262 KB

  cvt_p_kernel<<<128, 256, 0, stream>>>((const float4*)pin, (ushort4*)pb);
  rpe_kernel<<<1024, 256, 0, stream>>>(qin, pb, (float*)d_out);
}

// Round 7
// 34.958 us; speedup vs baseline: 1.0725x; 1.0394x over previous
//
#include <hip/hip_runtime.h>
#include <hip/hip_bf16.h>
#include <stdint.h>

// RelativePositionalEmbedding: out[bh, q, k] = dot(q[bh,q,:], pos_emb[q-k+1023,:]) / 8
// B*H = 32, L = 1024, D = 64. Output (32,1024,1024) fp32 = 134 MB -> write-BW-bound.
//
// R6 = proven-positive pieces only:
//  - R2 interleaved pair-flush (256B runs, stores spread through K-loop,
//    accA/accB only -> ~90 VGPR -> 4 waves/SIMD)
//  - R3 Q-direct (fp32 Q converted in-register; cvt kernel is P-only)
//  - regular stores (NT was the R3 regression: defeats L2 write-coalescing)
//  - R3 FIFO-verified waits: t0,t1->4; t2..6->36; t7->32 (stage(t) always
//    drained; flush stores never drained mid-loop)

#define LSEQ 1024
#define DDIM 64

typedef __attribute__((ext_vector_type(8))) short bf16x8;
typedef __attribute__((ext_vector_type(16))) float f32x16;

__device__ __forceinline__ unsigned short f2b(float f) {
  union { float f; unsigned u; } c; c.f = f;
  unsigned u = c.u;
  u += 0x7fffu + ((u >> 16) & 1u);   // round-to-nearest-even
  return (unsigned short)(u >> 16);
}

// Convert pos_emb to bf16 in workspace: 131,008 f32 = 32,752 float4.
__global__ __launch_bounds__(256) void cvt_p_kernel(
    const float4* __restrict__ p4, ushort4* __restrict__ pb) {
  int j = blockIdx.x * 256 + threadIdx.x;
  if (j < 32752) {
    float4 v = p4[j];
    ushort4 o;
    o.x = f2b(v.x); o.y = f2b(v.y); o.z = f2b(v.z); o.w = f2b(v.w);
    pb[j] = o;
  }
}

// One workgroup (4 waves) per q. Wave w owns columns [w*256, w*256+256), 8 tiles.
// mfma_f32_32x32x16_bf16: A row = lane&31, k = 16*s + 8*(lane>>5)+j
//                         B col = lane&31 (-> P row q+1023-n), same k
//                         D col = lane&31, row = (r&3)+8*(r>>2)+4*(lane>>5)
__global__ __launch_bounds__(256) void rpe_kernel(
    const float* __restrict__ Qf, const short* __restrict__ Pb,
    float* __restrict__ out) {
  __shared__ short lds[4][2][2048];           // [wave][buf][4KB band]
  // XCD-chunked q: XCD x gets q in [x*128, x*128+128) (1024 = 8*128, bijective)
  const int bid  = (int)blockIdx.x;
  const int q    = ((bid & 7) << 7) + (bid >> 3);
  const int tid  = (int)threadIdx.x;
  const int lane = tid & 63;
  const int wave = tid >> 6;
  const int l31  = lane & 31;
  const int hi   = lane >> 5;
  const int nbase = wave << 8;

  // pre-swizzled gload_lds SOURCE offset (rule #21): row-in-8 = lane>>3,
  // col16 = (lane&7) ^ (lane>>3); LDS dest stays linear lane*16.
  const int lane_off = ((lane >> 3) << 7) + ((((lane & 7) ^ (lane >> 3))) << 4);
  const char* Pc = (const char*)Pb;           // P row stride 128B

  auto STAGE = [&](int tt, int buf) {
    const int lo = q + 992 - nbase - (tt << 5);   // band rows [lo, lo+31]
    const char* src = Pc + ((size_t)lo << 7) + lane_off;
#pragma unroll
    for (int j = 0; j < 4; ++j)
      __builtin_amdgcn_global_load_lds(
          (const __attribute__((address_space(1))) void*)(src + (j << 10)),
          (__attribute__((address_space(3))) void*)&lds[wave][buf][j << 9],
          16, 0, 0);
  };

  STAGE(0, 0);                                // vm: stage0 (4)

  // A fragments from fp32 Q, scaled by 1/8 (exact) and converted in-register.
  // Qf[m = l31][q][16s + 8hi + j], j = 0..7 -> 2 x dwordx4 per s.
  bf16x8 a[4];
  {
    const float* qp = Qf + ((size_t)((l31 << 10) + q)) * DDIM + (hi << 3);
#pragma unroll
    for (int s = 0; s < 4; ++s) {
      float4 u = *(const float4*)(qp + 16 * s);
      float4 v = *(const float4*)(qp + 16 * s + 4);
      bf16x8 t;
      t[0] = (short)f2b(u.x * 0.125f); t[1] = (short)f2b(u.y * 0.125f);
      t[2] = (short)f2b(u.z * 0.125f); t[3] = (short)f2b(u.w * 0.125f);
      t[4] = (short)f2b(v.x * 0.125f); t[5] = (short)f2b(v.y * 0.125f);
      t[6] = (short)f2b(v.z * 0.125f); t[7] = (short)f2b(v.w * 0.125f);
      a[s] = t;
    }
  }                                           // vm: Q (8), drained by compiler

  STAGE(1, 1);                                // vm: stage1 (4)

  const int rr = 31 - l31;                    // LDS row this lane reads
  const int rx = rr & 7;                      // its XOR key

  f32x16 accA, accB;
#pragma unroll
  for (int t = 0; t < 8; ++t) {
    // FIFO (issue order: stage0,Q,stage1 | t0:stage2 | t1:stage3,st01 |
    //  t2:stage4 | t3:stage5,st23 | t4:stage6 | t5:stage7,st45 | t6,t7:-):
    // t0: [stage1,stage2] after compiler's Q-drain -> vmcnt(4) (stage0 done)
    // t1: [stage1,stage2]=8 -> vmcnt(4) drains stage1
    // t2..6: worst case 72 outstanding; drain-to-36 always completes
    //        stage(t) and never requires flush stores younger than it
    // t7: [stage7(4), st45(32)] -> vmcnt(32) drains stage7, keeps st45 live
    if (t == 0 || t == 1)
      asm volatile("s_waitcnt vmcnt(4)" ::: "memory");
    else if (t == 7)
      asm volatile("s_waitcnt vmcnt(32)" ::: "memory");
    else
      asm volatile("s_waitcnt vmcnt(36)" ::: "memory");

    f32x16& acc = (t & 1) ? accB : accA;
#pragma unroll
    for (int r = 0; r < 16; ++r) acc[r] = 0.0f;

    const short* base = &lds[wave][t & 1][rr << 6];
#pragma unroll
    for (int s = 0; s < 4; ++s) {
      bf16x8 bfr = *(const bf16x8*)(base + (((hi + 2 * s) ^ rx) << 3));
      acc = __builtin_amdgcn_mfma_f32_32x32x16_bf16(a[s], bfr, acc, 0, 0, 0);
    }

    if (t < 6) STAGE(t + 2, t & 1);           // refill consumed buffer FIRST

    if (t & 1) {
      // flush tiles (t-1, t): per m-plane two adjacent 128B lines = 256B run
      float* ob = out + ((size_t)hi << 22) + (q << 10) + nbase + ((t - 1) << 5) + l31;
#pragma unroll
      for (int r = 0; r < 16; ++r) {
        const int m = (r & 3) + 8 * (r >> 2);
        ob[(size_t)m << 20]        = accA[r];
        ob[((size_t)m << 20) + 32] = accB[r];
      }
    }
  }
}

extern "C" void kernel_launch(void* const* d_in, const int* in_sizes, int n_in,
                              void* d_out, int out_size, void* d_ws, size_t ws_size,
                              hipStream_t stream) {
  const float* qin = (const float*)d_in[0];
  // d_in[1] (k) unused: only its length (1024) matters, which is fixed.
  const float* pin = (const float*)d_in[2];

  short* pb = (short*)d_ws;                  // 131,008 bf16 = 262 KB

  cvt_p_kernel<<<128, 256, 0, stream>>>((const float4*)pin, (ushort4*)pb);
  rpe_kernel<<<1024, 256, 0, stream>>>(qin, pb, (float*)d_out);
}